// Round 12
// baseline (178.939 us; speedup 1.0000x reference)
//
#include <hip/hip_runtime.h>
#include <hip/hip_bf16.h>

#define NPTS 8192
#define DDIM 128
#define MARGIN 0.2f
#define NEG_FLOOR 0.6f
#define SENT -1e30f
#define NCHUNK 32
#define CHUNK (NPTS / NCHUNK)      // 256 cols per chunk
#define BM 128                     // rows per block (4 waves x 32)
#define NSTEP 16                   // 16-col steps per chunk, per wave
#define NRB (NPTS / 256)           // 32 reduce blocks

typedef __attribute__((ext_vector_type(8))) short short8;
typedef __attribute__((ext_vector_type(4))) float f32x4;
typedef __attribute__((ext_vector_type(4))) unsigned int uint4v;
typedef __attribute__((ext_vector_type(4))) unsigned short ushort4v;

// ws layout (bytes):
//   xb      : [0, 2 MiB)            bf16 X
//   partA   : +0    float [32][NPTS]   (pass1: mp_part; pass2: sum_part)
//   partB   : +1M   float [32][NPTS]   (pass1: mn_part; pass2: flg_part)
//   maxpos  : +2M   float [NPTS]
//   maxneg  : +2M+32K
//   blksum/blkcnt : +2M+64K

__device__ __forceinline__ unsigned short f2bf(unsigned u) {
    return (unsigned short)((u + 0x7FFFu + ((u >> 16) & 1u)) >> 16);
}

__global__ __launch_bounds__(256) void k_convert(const uint4v* __restrict__ x,
                                                 ushort4v* __restrict__ xb) {
    int i = blockIdx.x * 256 + threadIdx.x;
    uint4v u = x[i];
    ushort4v o;
    o.x = f2bf(u.x); o.y = f2bf(u.y); o.z = f2bf(u.z); o.w = f2bf(u.w);
    xb[i] = o;
}

__device__ __forceinline__ void gload16(const unsigned char* g, unsigned char* l) {
    __builtin_amdgcn_global_load_lds(
        (const __attribute__((address_space(1))) unsigned int*)(const void*)g,
        (__attribute__((address_space(3))) unsigned int*)(void*)l, 16, 0, 0);
}

// Per-wave private 16-col tile, fragment order: slot(ks, lane) at byte
// ks*1024 + lane*16 holds global bytes (j0 + (lane&15))*256 + ks*64 + (lane>>4)*16.
// No cross-wave sharing -> no barriers; wave self-syncs with counted vmcnt.

#define WSTAGE(bufp_, stepi_)                                                        \
    do {                                                                             \
        const unsigned char* src_ =                                                  \
            xc + (size_t)(jbase + (stepi_)*16 + lr) * 256 + hi * 16;                 \
        gload16(src_ + 0,   (bufp_) + 0 * 1024);                                     \
        gload16(src_ + 64,  (bufp_) + 1 * 1024);                                     \
        gload16(src_ + 128, (bufp_) + 2 * 1024);                                     \
        gload16(src_ + 192, (bufp_) + 3 * 1024);                                     \
    } while (0)

#define MFMA8W(B_, acc0_, acc1_)                                                      \
    short8 b0_ = *(const short8*)((B_) + 0 * 1024 + lane * 16);                       \
    short8 b1_ = *(const short8*)((B_) + 1 * 1024 + lane * 16);                       \
    short8 b2_ = *(const short8*)((B_) + 2 * 1024 + lane * 16);                       \
    short8 b3_ = *(const short8*)((B_) + 3 * 1024 + lane * 16);                       \
    acc0_ = __builtin_amdgcn_mfma_f32_16x16x32_bf16(a[0][0], b0_, acc0_, 0, 0, 0);    \
    acc1_ = __builtin_amdgcn_mfma_f32_16x16x32_bf16(a[1][0], b0_, acc1_, 0, 0, 0);    \
    acc0_ = __builtin_amdgcn_mfma_f32_16x16x32_bf16(a[0][1], b1_, acc0_, 0, 0, 0);    \
    acc1_ = __builtin_amdgcn_mfma_f32_16x16x32_bf16(a[1][1], b1_, acc1_, 0, 0, 0);    \
    acc0_ = __builtin_amdgcn_mfma_f32_16x16x32_bf16(a[0][2], b2_, acc0_, 0, 0, 0);    \
    acc1_ = __builtin_amdgcn_mfma_f32_16x16x32_bf16(a[1][2], b2_, acc1_, 0, 0, 0);    \
    acc0_ = __builtin_amdgcn_mfma_f32_16x16x32_bf16(a[0][3], b3_, acc0_, 0, 0, 0);    \
    acc1_ = __builtin_amdgcn_mfma_f32_16x16x32_bf16(a[1][3], b3_, acc1_, 0, 0, 0);

// pass1 epilogue: diag handled only in the (wave-uniform) steps that contain it
#define COMPUTE_P1(B_, stepi_)                                                        \
    do {                                                                              \
        int j0_  = jbase + (stepi_) * 16;                                             \
        int tjv_ = ts[(stepi_) * 16 + lr];                                            \
        f32x4 acc0 = {0.f, 0.f, 0.f, 0.f}, acc1 = {0.f, 0.f, 0.f, 0.f};               \
        MFMA8W(B_, acc0, acc1)                                                        \
        if ((unsigned)(j0_ - rowbase) < 32u) {                                        \
            _Pragma("unroll")                                                         \
            for (int rg = 0; rg < 2; ++rg) {                                          \
                f32x4 accv = (rg == 0) ? acc0 : acc1;                                 \
                int dv_ = j0_ + lr - (rowbase + rg * 16 + hi * 4);                    \
                _Pragma("unroll")                                                     \
                for (int r = 0; r < 4; ++r) {                                         \
                    bool same_ = (tjv_ == trow[rg][r]);                               \
                    float s_   = accv[r];                                             \
                    mp[rg][r] = fmaxf(mp[rg][r], (same_ && dv_ != r) ? s_ : SENT);    \
                    mn[rg][r] = fmaxf(mn[rg][r], same_ ? SENT : s_);                  \
                }                                                                     \
            }                                                                         \
        } else {                                                                      \
            _Pragma("unroll")                                                         \
            for (int rg = 0; rg < 2; ++rg) {                                          \
                f32x4 accv = (rg == 0) ? acc0 : acc1;                                 \
                _Pragma("unroll")                                                     \
                for (int r = 0; r < 4; ++r) {                                         \
                    bool same_ = (tjv_ == trow[rg][r]);                               \
                    float s_   = accv[r];                                             \
                    mp[rg][r] = fmaxf(mp[rg][r], same_ ? s_ : SENT);                  \
                    mn[rg][r] = fmaxf(mn[rg][r], same_ ? SENT : s_);                  \
                }                                                                     \
            }                                                                         \
        }                                                                             \
    } while (0)

#define COMPUTE_P2(B_, stepi_)                                                        \
    do {                                                                              \
        int j0_  = jbase + (stepi_) * 16;                                             \
        int tjv_ = ts[(stepi_) * 16 + lr];                                            \
        f32x4 acc0 = {0.f, 0.f, 0.f, 0.f}, acc1 = {0.f, 0.f, 0.f, 0.f};               \
        MFMA8W(B_, acc0, acc1)                                                        \
        if ((unsigned)(j0_ - rowbase) < 32u) {                                        \
            _Pragma("unroll")                                                         \
            for (int rg = 0; rg < 2; ++rg) {                                          \
                f32x4 accv = (rg == 0) ? acc0 : acc1;                                 \
                int dv_ = j0_ + lr - (rowbase + rg * 16 + hi * 4);                    \
                _Pragma("unroll")                                                     \
                for (int r = 0; r < 4; ++r) {                                         \
                    bool same_ = (tjv_ == trow[rg][r]);                               \
                    float s_   = accv[r];                                             \
                    bool psel_ = same_ && (dv_ != r) && (s_ < pos_lim[rg][r]);        \
                    bool nsel_ = (!same_) && (s_ > neg_th[rg][r]);                    \
                    sumP[rg][r] += psel_ ? (1.0f - s_) : 0.0f;                        \
                    sumN[rg][r] += nsel_ ? s_ : 0.0f;                                 \
                }                                                                     \
            }                                                                         \
        } else {                                                                      \
            _Pragma("unroll")                                                         \
            for (int rg = 0; rg < 2; ++rg) {                                          \
                f32x4 accv = (rg == 0) ? acc0 : acc1;                                 \
                _Pragma("unroll")                                                     \
                for (int r = 0; r < 4; ++r) {                                         \
                    bool same_ = (tjv_ == trow[rg][r]);                               \
                    float s_   = accv[r];                                             \
                    bool psel_ = same_ && (s_ < pos_lim[rg][r]);                      \
                    bool nsel_ = (!same_) && (s_ > neg_th[rg][r]);                    \
                    sumP[rg][r] += psel_ ? (1.0f - s_) : 0.0f;                        \
                    sumN[rg][r] += nsel_ ? s_ : 0.0f;                                 \
                }                                                                     \
            }                                                                         \
        }                                                                             \
    } while (0)

// Steady-state: 4 loads (current step) + 4 just-issued (next) in flight;
// vmcnt(4) retires the current step's 4 without draining the next's.
#define VMC4 asm volatile("s_waitcnt vmcnt(4)" ::: "memory")

__global__ __launch_bounds__(256, 4) void k_pass1(const unsigned short* __restrict__ xb,
                                                  const int* __restrict__ tg,
                                                  float* __restrict__ mp_part,
                                                  float* __restrict__ mn_part) {
    __shared__ __align__(16) unsigned char smB[4 * 2 * 4096];  // 32 KB: [wave][buf]
    __shared__ int ts[CHUNK];                                  // 1 KB

    const unsigned char* xc = (const unsigned char*)xb;
    int tid  = threadIdx.x;
    int lane = tid & 63, w = tid >> 6, lr = lane & 15, hi = lane >> 4;
    int bb    = blockIdx.x;
    int chunk = bb & (NCHUNK - 1);
    int rb    = bb >> 5;
    int jbase = chunk * CHUNK;
    int rowbase = rb * BM + w * 32;
    unsigned char* smW = smB + w * 8192;

    ts[tid] = tg[jbase + tid];

    WSTAGE(smW, 0);   // prologue: step 0 -> buf0

    short8 a[2][4];
#pragma unroll
    for (int rg = 0; rg < 2; ++rg)
#pragma unroll
        for (int ks = 0; ks < 4; ++ks)
            a[rg][ks] = *(const short8*)(xc + (size_t)(rowbase + rg * 16 + lr) * 256 + ks * 64 + hi * 16);

    int trow[2][4];
#pragma unroll
    for (int rg = 0; rg < 2; ++rg)
#pragma unroll
        for (int r = 0; r < 4; ++r)
            trow[rg][r] = tg[rowbase + rg * 16 + hi * 4 + r];

    float mp[2][4], mn[2][4];
#pragma unroll
    for (int rg = 0; rg < 2; ++rg)
#pragma unroll
        for (int r = 0; r < 4; ++r) { mp[rg][r] = SENT; mn[rg][r] = SENT; }

    __syncthreads();  // ts ready (also drains prologue stage; one-time)

    for (int s2 = 0; s2 < NSTEP; s2 += 2) {
        WSTAGE(smW + 4096, s2 + 1);
        VMC4;
        COMPUTE_P1(smW, s2);
        WSTAGE(smW, (s2 + 2) & (NSTEP - 1));
        VMC4;
        COMPUTE_P1(smW + 4096, s2 + 1);
    }

#pragma unroll
    for (int off = 1; off < 16; off <<= 1)
#pragma unroll
        for (int rg = 0; rg < 2; ++rg)
#pragma unroll
            for (int r = 0; r < 4; ++r) {
                mp[rg][r] = fmaxf(mp[rg][r], __shfl_xor(mp[rg][r], off, 64));
                mn[rg][r] = fmaxf(mn[rg][r], __shfl_xor(mn[rg][r], off, 64));
            }
    if (lr == 0) {
#pragma unroll
        for (int rg = 0; rg < 2; ++rg)
#pragma unroll
            for (int r = 0; r < 4; ++r) {
                int row = rowbase + rg * 16 + hi * 4 + r;
                mp_part[chunk * NPTS + row] = mp[rg][r];
                mn_part[chunk * NPTS + row] = mn[rg][r];
            }
    }
}

__global__ __launch_bounds__(256) void k_red1(const float* __restrict__ mp_part,
                                              const float* __restrict__ mn_part,
                                              float* __restrict__ maxpos,
                                              float* __restrict__ maxneg) {
    int row = blockIdx.x * 256 + threadIdx.x;
    float mp = SENT, mn = SENT;
#pragma unroll
    for (int c = 0; c < NCHUNK; ++c) {
        mp = fmaxf(mp, mp_part[c * NPTS + row]);
        mn = fmaxf(mn, mn_part[c * NPTS + row]);
    }
    maxpos[row] = mp;
    maxneg[row] = mn;
}

__global__ __launch_bounds__(256, 4) void k_pass2(const unsigned short* __restrict__ xb,
                                                  const int* __restrict__ tg,
                                                  const float* __restrict__ maxpos,
                                                  const float* __restrict__ maxneg,
                                                  float* __restrict__ sum_part,
                                                  int* __restrict__ flg_part) {
    __shared__ __align__(16) unsigned char smB[4 * 2 * 4096];
    __shared__ int ts[CHUNK];

    const unsigned char* xc = (const unsigned char*)xb;
    int tid  = threadIdx.x;
    int lane = tid & 63, w = tid >> 6, lr = lane & 15, hi = lane >> 4;
    int bb    = blockIdx.x;
    int chunk = bb & (NCHUNK - 1);
    int rb    = bb >> 5;
    int jbase = chunk * CHUNK;
    int rowbase = rb * BM + w * 32;
    unsigned char* smW = smB + w * 8192;

    ts[tid] = tg[jbase + tid];

    WSTAGE(smW, 0);

    short8 a[2][4];
#pragma unroll
    for (int rg = 0; rg < 2; ++rg)
#pragma unroll
        for (int ks = 0; ks < 4; ++ks)
            a[rg][ks] = *(const short8*)(xc + (size_t)(rowbase + rg * 16 + lr) * 256 + ks * 64 + hi * 16);

    int trow[2][4];
    float pos_lim[2][4], neg_th[2][4];
#pragma unroll
    for (int rg = 0; rg < 2; ++rg)
#pragma unroll
        for (int r = 0; r < 4; ++r) {
            int row         = rowbase + rg * 16 + hi * 4 + r;
            trow[rg][r]     = tg[row];
            pos_lim[rg][r]  = maxneg[row] + MARGIN;
            neg_th[rg][r]   = fmaxf(NEG_FLOOR, maxpos[row]) - MARGIN;
        }

    float sumP[2][4] = {{0.f,0.f,0.f,0.f},{0.f,0.f,0.f,0.f}};
    float sumN[2][4] = {{0.f,0.f,0.f,0.f},{0.f,0.f,0.f,0.f}};

    __syncthreads();

    for (int s2 = 0; s2 < NSTEP; s2 += 2) {
        WSTAGE(smW + 4096, s2 + 1);
        VMC4;
        COMPUTE_P2(smW, s2);
        WSTAGE(smW, (s2 + 2) & (NSTEP - 1));
        VMC4;
        COMPUTE_P2(smW + 4096, s2 + 1);
    }

    // any selected negative <=> sumN > 0 (selected negs have s > 0.4)
    float sum[2][4];
    int an = 0;
#pragma unroll
    for (int rg = 0; rg < 2; ++rg)
#pragma unroll
        for (int r = 0; r < 4; ++r) {
            sum[rg][r] = sumP[rg][r] + sumN[rg][r];
            an |= (sumN[rg][r] > 0.f) ? (1 << (rg * 4 + r)) : 0;
        }

#pragma unroll
    for (int off = 1; off < 16; off <<= 1) {
        an |= __shfl_xor(an, off, 64);
#pragma unroll
        for (int rg = 0; rg < 2; ++rg)
#pragma unroll
            for (int r = 0; r < 4; ++r)
                sum[rg][r] += __shfl_xor(sum[rg][r], off, 64);
    }
    if (lr == 0) {
#pragma unroll
        for (int rg = 0; rg < 2; ++rg)
#pragma unroll
            for (int r = 0; r < 4; ++r) {
                int row = rowbase + rg * 16 + hi * 4 + r;
                sum_part[chunk * NPTS + row] = sum[rg][r];
                flg_part[chunk * NPTS + row] = (an >> (rg * 4 + r)) & 1;
            }
    }
}

__global__ __launch_bounds__(256) void k_red2(const float* __restrict__ maxpos,
                                              const float* __restrict__ sum_part,
                                              const int* __restrict__ flg_part,
                                              float* __restrict__ blksum,
                                              float* __restrict__ blkcnt) {
    __shared__ float sf[256];
    __shared__ int   si[256];
    int t   = threadIdx.x;
    int row = blockIdx.x * 256 + t;

    bool hp = maxpos[row] > -1e29f;
    float rs = 0.f;
    int   fl = 0;
#pragma unroll
    for (int ch = 0; ch < NCHUNK; ++ch) {
        rs += sum_part[ch * NPTS + row];
        fl |= flg_part[ch * NPTS + row];
    }
    sf[t] = hp ? rs : 0.f;
    si[t] = (hp && fl) ? 1 : 0;
    __syncthreads();
    for (int off = 128; off > 0; off >>= 1) {
        if (t < off) { sf[t] += sf[t + off]; si[t] += si[t + off]; }
        __syncthreads();
    }
    if (t == 0) {
        blksum[blockIdx.x] = sf[0];
        blkcnt[blockIdx.x] = (float)si[0];
    }
}

__global__ __launch_bounds__(64) void k_final(const float* __restrict__ blksum,
                                              const float* __restrict__ blkcnt,
                                              float* __restrict__ out) {
    int t = threadIdx.x;
    float s = (t < NRB) ? blksum[t] : 0.f;
    float c = (t < NRB) ? blkcnt[t] : 0.f;
#pragma unroll
    for (int off = 32; off > 0; off >>= 1) {
        s += __shfl_xor(s, off, 64);
        c += __shfl_xor(c, off, 64);
    }
    if (t == 0) {
        out[0] = s / (float)NPTS;
        out[1] = c;
    }
}

extern "C" void kernel_launch(void* const* d_in, const int* in_sizes, int n_in,
                              void* d_out, int out_size, void* d_ws, size_t ws_size,
                              hipStream_t stream) {
    const float* x  = (const float*)d_in[0];
    const int*   tg = (const int*)d_in[1];
    float* out = (float*)d_out;

    unsigned short* xb = (unsigned short*)d_ws;
    char* base = (char*)d_ws + (size_t)NPTS * DDIM * 2;
    float* partA = (float*)(base);                                  // mp_part / sum_part
    float* partB = (float*)(base + (size_t)NCHUNK * NPTS * 4);      // mn_part / flg_part
    float* maxpos = (float*)(base + 2 * (size_t)NCHUNK * NPTS * 4);
    float* maxneg = (float*)(base + 2 * (size_t)NCHUNK * NPTS * 4 + NPTS * 4);
    float* blksum = (float*)(base + 2 * (size_t)NCHUNK * NPTS * 4 + 2 * NPTS * 4);
    float* blkcnt = blksum + NRB;

    k_convert<<<(NPTS * DDIM / 4) / 256, 256, 0, stream>>>((const uint4v*)x, (ushort4v*)xb);
    k_pass1<<<(NPTS / BM) * NCHUNK, 256, 0, stream>>>(xb, tg, partA, partB);
    k_red1<<<NPTS / 256, 256, 0, stream>>>(partA, partB, maxpos, maxneg);
    k_pass2<<<(NPTS / BM) * NCHUNK, 256, 0, stream>>>(xb, tg, maxpos, maxneg, partA, (int*)partB);
    k_red2<<<NRB, 256, 0, stream>>>(maxpos, partA, (const int*)partB, blksum, blkcnt);
    k_final<<<1, 64, 0, stream>>>(blksum, blkcnt, out);
}

// Round 13
// 78.512 us; speedup vs baseline: 2.2791x; 2.2791x over previous
//
#include <hip/hip_runtime.h>
#include <hip/hip_bf16.h>

#define NPTS 8192
#define DDIM 128
#define MARGIN 0.2f
#define NEG_FLOOR 0.6f
#define SENT -1e30f
#define NCHUNK 16
#define CHUNK (NPTS / NCHUNK)      // 512 cols per chunk
#define BM 128                     // rows per block (4 waves x 32)
#define JT 64                      // cols staged per step
#define NSTEP (CHUNK / JT)         // 8
#define NRB (NPTS / 256)           // 32 reduce blocks

typedef __attribute__((ext_vector_type(8))) short short8;
typedef __attribute__((ext_vector_type(4))) float f32x4;
typedef __attribute__((ext_vector_type(4))) unsigned int uint4v;
typedef __attribute__((ext_vector_type(4))) unsigned short ushort4v;

// ws layout (bytes):
//   xb      : [0, 2 MiB)            bf16 X
//   partA   : +0      float [16][NPTS]  (pass1: mp_part; pass2: sum_part)
//   partB   : +512K   float [16][NPTS]  (pass1: mn_part; pass2: flg_part)
//   maxpos  : +1M     float [NPTS]
//   maxneg  : +1M+32K
//   blksum/blkcnt : +1M+64K

__device__ __forceinline__ unsigned short f2bf(unsigned u) {
    return (unsigned short)((u + 0x7FFFu + ((u >> 16) & 1u)) >> 16);
}

__global__ __launch_bounds__(256) void k_convert(const uint4v* __restrict__ x,
                                                 ushort4v* __restrict__ xb) {
    int i = blockIdx.x * 256 + threadIdx.x;
    uint4v u = x[i];
    ushort4v o;
    o.x = f2bf(u.x); o.y = f2bf(u.y); o.z = f2bf(u.z); o.w = f2bf(u.w);
    xb[i] = o;
}

__device__ __forceinline__ void gload16(const unsigned char* g, unsigned char* l) {
    __builtin_amdgcn_global_load_lds(
        (const __attribute__((address_space(1))) unsigned int*)(const void*)g,
        (__attribute__((address_space(3))) unsigned int*)(void*)l, 16, 0, 0);
}

// LDS B-tile layout = fragment order: slot(cg, ks, lane) at byte
// cg*4096 + ks*1024 + lane*16 holds global bytes
// (j0 + cg*16 + (lane&15))*256 + ks*64 + (lane>>4)*16.
// Wave w stages cg=w; every hot ds_read_b128 is base + lane*16 (conflict-free).

#define MFMA8(B_, cg_, acc0_, acc1_)                                                  \
    short8 b0_ = *(const short8*)((B_) + (cg_)*4096 + 0 * 1024 + lane * 16);          \
    short8 b1_ = *(const short8*)((B_) + (cg_)*4096 + 1 * 1024 + lane * 16);          \
    short8 b2_ = *(const short8*)((B_) + (cg_)*4096 + 2 * 1024 + lane * 16);          \
    short8 b3_ = *(const short8*)((B_) + (cg_)*4096 + 3 * 1024 + lane * 16);          \
    acc0_ = __builtin_amdgcn_mfma_f32_16x16x32_bf16(a[0][0], b0_, acc0_, 0, 0, 0);    \
    acc1_ = __builtin_amdgcn_mfma_f32_16x16x32_bf16(a[1][0], b0_, acc1_, 0, 0, 0);    \
    acc0_ = __builtin_amdgcn_mfma_f32_16x16x32_bf16(a[0][1], b1_, acc0_, 0, 0, 0);    \
    acc1_ = __builtin_amdgcn_mfma_f32_16x16x32_bf16(a[1][1], b1_, acc1_, 0, 0, 0);    \
    acc0_ = __builtin_amdgcn_mfma_f32_16x16x32_bf16(a[0][2], b2_, acc0_, 0, 0, 0);    \
    acc1_ = __builtin_amdgcn_mfma_f32_16x16x32_bf16(a[1][2], b2_, acc1_, 0, 0, 0);    \
    acc0_ = __builtin_amdgcn_mfma_f32_16x16x32_bf16(a[0][3], b3_, acc0_, 0, 0, 0);    \
    acc1_ = __builtin_amdgcn_mfma_f32_16x16x32_bf16(a[1][3], b3_, acc1_, 0, 0, 0);

__global__ __launch_bounds__(256, 4) void k_pass1(const unsigned short* __restrict__ xb,
                                                  const int* __restrict__ tg,
                                                  float* __restrict__ mp_part,
                                                  float* __restrict__ mn_part) {
    __shared__ __align__(16) unsigned char smB[JT * 256];  // 16 KB
    __shared__ int ts[CHUNK];                              // 2 KB

    const unsigned char* xc = (const unsigned char*)xb;
    int tid  = threadIdx.x;
    int lane = tid & 63, w = tid >> 6, lr = lane & 15, hi = lane >> 4;
    int bb    = blockIdx.x;
    int chunk = bb & (NCHUNK - 1);
    int rb    = bb >> 4;
    int jbase = chunk * CHUNK;
    int rowbase = rb * BM + w * 32;

    ts[tid]       = tg[jbase + tid];
    ts[tid + 256] = tg[jbase + 256 + tid];

    short8 a[2][4];
#pragma unroll
    for (int rg = 0; rg < 2; ++rg)
#pragma unroll
        for (int ks = 0; ks < 4; ++ks)
            a[rg][ks] = *(const short8*)(xc + (size_t)(rowbase + rg * 16 + lr) * 256 + ks * 64 + hi * 16);

    int trow[2][4];
#pragma unroll
    for (int rg = 0; rg < 2; ++rg)
#pragma unroll
        for (int r = 0; r < 4; ++r)
            trow[rg][r] = tg[rowbase + rg * 16 + hi * 4 + r];

    float mp[2][4], mn[2][4];
#pragma unroll
    for (int rg = 0; rg < 2; ++rg)
#pragma unroll
        for (int r = 0; r < 4; ++r) { mp[rg][r] = SENT; mn[rg][r] = SENT; }

    for (int step = 0; step < NSTEP; ++step) {
        int j0 = jbase + step * JT;
        __syncthreads();  // prior compute done (iter 0: ts ready)
        const unsigned char* src = xc + (size_t)(j0 + w * 16 + lr) * 256 + hi * 16;
#pragma unroll
        for (int r = 0; r < 4; ++r)
            gload16(src + r * 64, smB + w * 4096 + r * 1024);
        __syncthreads();  // tile ready

        if ((unsigned)(rowbase - j0) < (unsigned)JT) {
            // diag-containing step (wave-uniform): full dv check
#pragma unroll
            for (int cg = 0; cg < 4; ++cg) {
                int col = j0 + cg * 16 + lr;
                int tjv = ts[step * 64 + cg * 16 + lr];
                f32x4 acc0 = {0.f, 0.f, 0.f, 0.f}, acc1 = {0.f, 0.f, 0.f, 0.f};
                MFMA8(smB, cg, acc0, acc1)
#pragma unroll
                for (int rg = 0; rg < 2; ++rg) {
                    f32x4 accv = (rg == 0) ? acc0 : acc1;
                    int dv = col - (rowbase + rg * 16 + hi * 4);  // diag when dv == r
#pragma unroll
                    for (int r = 0; r < 4; ++r) {
                        bool same = (tjv == trow[rg][r]);
                        float s   = accv[r];
                        mp[rg][r] = fmaxf(mp[rg][r], (same && dv != r) ? s : SENT);
                        mn[rg][r] = fmaxf(mn[rg][r], same ? SENT : s);
                    }
                }
            }
        } else {
            // no diagonal in this step: drop the dv compare
#pragma unroll
            for (int cg = 0; cg < 4; ++cg) {
                int tjv = ts[step * 64 + cg * 16 + lr];
                f32x4 acc0 = {0.f, 0.f, 0.f, 0.f}, acc1 = {0.f, 0.f, 0.f, 0.f};
                MFMA8(smB, cg, acc0, acc1)
#pragma unroll
                for (int rg = 0; rg < 2; ++rg) {
                    f32x4 accv = (rg == 0) ? acc0 : acc1;
#pragma unroll
                    for (int r = 0; r < 4; ++r) {
                        bool same = (tjv == trow[rg][r]);
                        float s   = accv[r];
                        mp[rg][r] = fmaxf(mp[rg][r], same ? s : SENT);
                        mn[rg][r] = fmaxf(mn[rg][r], same ? SENT : s);
                    }
                }
            }
        }
    }

#pragma unroll
    for (int off = 1; off < 16; off <<= 1)
#pragma unroll
        for (int rg = 0; rg < 2; ++rg)
#pragma unroll
            for (int r = 0; r < 4; ++r) {
                mp[rg][r] = fmaxf(mp[rg][r], __shfl_xor(mp[rg][r], off, 64));
                mn[rg][r] = fmaxf(mn[rg][r], __shfl_xor(mn[rg][r], off, 64));
            }
    if (lr == 0) {
#pragma unroll
        for (int rg = 0; rg < 2; ++rg)
#pragma unroll
            for (int r = 0; r < 4; ++r) {
                int row = rowbase + rg * 16 + hi * 4 + r;
                mp_part[chunk * NPTS + row] = mp[rg][r];
                mn_part[chunk * NPTS + row] = mn[rg][r];
            }
    }
}

__global__ __launch_bounds__(256) void k_red1(const float* __restrict__ mp_part,
                                              const float* __restrict__ mn_part,
                                              float* __restrict__ maxpos,
                                              float* __restrict__ maxneg) {
    int row = blockIdx.x * 256 + threadIdx.x;
    float mp = SENT, mn = SENT;
#pragma unroll
    for (int c = 0; c < NCHUNK; ++c) {
        mp = fmaxf(mp, mp_part[c * NPTS + row]);
        mn = fmaxf(mn, mn_part[c * NPTS + row]);
    }
    maxpos[row] = mp;
    maxneg[row] = mn;
}

__global__ __launch_bounds__(256, 4) void k_pass2(const unsigned short* __restrict__ xb,
                                                  const int* __restrict__ tg,
                                                  const float* __restrict__ maxpos,
                                                  const float* __restrict__ maxneg,
                                                  float* __restrict__ sum_part,
                                                  int* __restrict__ flg_part) {
    __shared__ __align__(16) unsigned char smB[JT * 256];
    __shared__ int ts[CHUNK];

    const unsigned char* xc = (const unsigned char*)xb;
    int tid  = threadIdx.x;
    int lane = tid & 63, w = tid >> 6, lr = lane & 15, hi = lane >> 4;
    int bb    = blockIdx.x;
    int chunk = bb & (NCHUNK - 1);
    int rb    = bb >> 4;
    int jbase = chunk * CHUNK;
    int rowbase = rb * BM + w * 32;

    ts[tid]       = tg[jbase + tid];
    ts[tid + 256] = tg[jbase + 256 + tid];

    short8 a[2][4];
#pragma unroll
    for (int rg = 0; rg < 2; ++rg)
#pragma unroll
        for (int ks = 0; ks < 4; ++ks)
            a[rg][ks] = *(const short8*)(xc + (size_t)(rowbase + rg * 16 + lr) * 256 + ks * 64 + hi * 16);

    int trow[2][4];
    float pos_lim[2][4], neg_th[2][4];
#pragma unroll
    for (int rg = 0; rg < 2; ++rg)
#pragma unroll
        for (int r = 0; r < 4; ++r) {
            int row         = rowbase + rg * 16 + hi * 4 + r;
            trow[rg][r]     = tg[row];
            pos_lim[rg][r]  = maxneg[row] + MARGIN;
            neg_th[rg][r]   = fmaxf(NEG_FLOOR, maxpos[row]) - MARGIN;
        }

    float sumP[2][4] = {{0.f,0.f,0.f,0.f},{0.f,0.f,0.f,0.f}};
    float sumN[2][4] = {{0.f,0.f,0.f,0.f},{0.f,0.f,0.f,0.f}};

    for (int step = 0; step < NSTEP; ++step) {
        int j0 = jbase + step * JT;
        __syncthreads();
        const unsigned char* src = xc + (size_t)(j0 + w * 16 + lr) * 256 + hi * 16;
#pragma unroll
        for (int r = 0; r < 4; ++r)
            gload16(src + r * 64, smB + w * 4096 + r * 1024);
        __syncthreads();

        if ((unsigned)(rowbase - j0) < (unsigned)JT) {
#pragma unroll
            for (int cg = 0; cg < 4; ++cg) {
                int col = j0 + cg * 16 + lr;
                int tjv = ts[step * 64 + cg * 16 + lr];
                f32x4 acc0 = {0.f, 0.f, 0.f, 0.f}, acc1 = {0.f, 0.f, 0.f, 0.f};
                MFMA8(smB, cg, acc0, acc1)
#pragma unroll
                for (int rg = 0; rg < 2; ++rg) {
                    f32x4 accv = (rg == 0) ? acc0 : acc1;
                    int dv = col - (rowbase + rg * 16 + hi * 4);
#pragma unroll
                    for (int r = 0; r < 4; ++r) {
                        bool same = (tjv == trow[rg][r]);
                        float s   = accv[r];
                        bool psel = same && (dv != r) && (s < pos_lim[rg][r]);
                        bool nsel = (!same) && (s > neg_th[rg][r]);
                        sumP[rg][r] += psel ? (1.0f - s) : 0.0f;
                        sumN[rg][r] += nsel ? s : 0.0f;
                    }
                }
            }
        } else {
#pragma unroll
            for (int cg = 0; cg < 4; ++cg) {
                int tjv = ts[step * 64 + cg * 16 + lr];
                f32x4 acc0 = {0.f, 0.f, 0.f, 0.f}, acc1 = {0.f, 0.f, 0.f, 0.f};
                MFMA8(smB, cg, acc0, acc1)
#pragma unroll
                for (int rg = 0; rg < 2; ++rg) {
                    f32x4 accv = (rg == 0) ? acc0 : acc1;
#pragma unroll
                    for (int r = 0; r < 4; ++r) {
                        bool same = (tjv == trow[rg][r]);
                        float s   = accv[r];
                        bool psel = same && (s < pos_lim[rg][r]);
                        bool nsel = (!same) && (s > neg_th[rg][r]);
                        sumP[rg][r] += psel ? (1.0f - s) : 0.0f;
                        sumN[rg][r] += nsel ? s : 0.0f;
                    }
                }
            }
        }
    }

    // any selected negative <=> sumN > 0 (selected negs have s > 0.4)
    float sum[2][4];
    int an = 0;
#pragma unroll
    for (int rg = 0; rg < 2; ++rg)
#pragma unroll
        for (int r = 0; r < 4; ++r) {
            sum[rg][r] = sumP[rg][r] + sumN[rg][r];
            an |= (sumN[rg][r] > 0.f) ? (1 << (rg * 4 + r)) : 0;
        }

#pragma unroll
    for (int off = 1; off < 16; off <<= 1) {
        an |= __shfl_xor(an, off, 64);
#pragma unroll
        for (int rg = 0; rg < 2; ++rg)
#pragma unroll
            for (int r = 0; r < 4; ++r)
                sum[rg][r] += __shfl_xor(sum[rg][r], off, 64);
    }
    if (lr == 0) {
#pragma unroll
        for (int rg = 0; rg < 2; ++rg)
#pragma unroll
            for (int r = 0; r < 4; ++r) {
                int row = rowbase + rg * 16 + hi * 4 + r;
                sum_part[chunk * NPTS + row] = sum[rg][r];
                flg_part[chunk * NPTS + row] = (an >> (rg * 4 + r)) & 1;
            }
    }
}

__global__ __launch_bounds__(256) void k_red2(const float* __restrict__ maxpos,
                                              const float* __restrict__ sum_part,
                                              const int* __restrict__ flg_part,
                                              float* __restrict__ blksum,
                                              float* __restrict__ blkcnt) {
    __shared__ float sf[256];
    __shared__ int   si[256];
    int t   = threadIdx.x;
    int row = blockIdx.x * 256 + t;

    bool hp = maxpos[row] > -1e29f;
    float rs = 0.f;
    int   fl = 0;
#pragma unroll
    for (int ch = 0; ch < NCHUNK; ++ch) {
        rs += sum_part[ch * NPTS + row];
        fl |= flg_part[ch * NPTS + row];
    }
    sf[t] = hp ? rs : 0.f;
    si[t] = (hp && fl) ? 1 : 0;
    __syncthreads();
    for (int off = 128; off > 0; off >>= 1) {
        if (t < off) { sf[t] += sf[t + off]; si[t] += si[t + off]; }
        __syncthreads();
    }
    if (t == 0) {
        blksum[blockIdx.x] = sf[0];
        blkcnt[blockIdx.x] = (float)si[0];
    }
}

__global__ __launch_bounds__(64) void k_final(const float* __restrict__ blksum,
                                              const float* __restrict__ blkcnt,
                                              float* __restrict__ out) {
    int t = threadIdx.x;
    float s = (t < NRB) ? blksum[t] : 0.f;
    float c = (t < NRB) ? blkcnt[t] : 0.f;
#pragma unroll
    for (int off = 32; off > 0; off >>= 1) {
        s += __shfl_xor(s, off, 64);
        c += __shfl_xor(c, off, 64);
    }
    if (t == 0) {
        out[0] = s / (float)NPTS;
        out[1] = c;
    }
}

extern "C" void kernel_launch(void* const* d_in, const int* in_sizes, int n_in,
                              void* d_out, int out_size, void* d_ws, size_t ws_size,
                              hipStream_t stream) {
    const float* x  = (const float*)d_in[0];
    const int*   tg = (const int*)d_in[1];
    float* out = (float*)d_out;

    unsigned short* xb = (unsigned short*)d_ws;
    char* base = (char*)d_ws + (size_t)NPTS * DDIM * 2;
    float* partA = (float*)(base);                                  // mp_part / sum_part
    float* partB = (float*)(base + (size_t)NCHUNK * NPTS * 4);      // mn_part / flg_part
    float* maxpos = (float*)(base + 2 * (size_t)NCHUNK * NPTS * 4);
    float* maxneg = (float*)(base + 2 * (size_t)NCHUNK * NPTS * 4 + NPTS * 4);
    float* blksum = (float*)(base + 2 * (size_t)NCHUNK * NPTS * 4 + 2 * NPTS * 4);
    float* blkcnt = blksum + NRB;

    k_convert<<<(NPTS * DDIM / 4) / 256, 256, 0, stream>>>((const uint4v*)x, (ushort4v*)xb);
    k_pass1<<<(NPTS / BM) * NCHUNK, 256, 0, stream>>>(xb, tg, partA, partB);
    k_red1<<<NPTS / 256, 256, 0, stream>>>(partA, partB, maxpos, maxneg);
    k_pass2<<<(NPTS / BM) * NCHUNK, 256, 0, stream>>>(xb, tg, maxpos, maxneg, partA, (int*)partB);
    k_red2<<<NRB, 256, 0, stream>>>(maxpos, partA, (const int*)partB, blksum, blkcnt);
    k_final<<<1, 64, 0, stream>>>(blksum, blkcnt, out);
}